// Round 6
// baseline (354.640 us; speedup 1.0000x reference)
//
#include <hip/hip_runtime.h>
#include <cfloat>

#define BB 4
#define LL 2048
#define DMODEL 256
#define DINNER 512
#define DSTATE 16
#define DTRANK 16
#define HID 128
#define NCLS 4
#define CH 32
#define NC 64
#define LP 2050   // padded rows per batch for f1 (guard row front+back)

typedef unsigned short u16;
typedef __attribute__((ext_vector_type(8))) short bf16x8;
typedef __attribute__((ext_vector_type(4))) float f32x4;

__device__ inline u16 f2b(float v) {
  union { float f; unsigned u; } c; c.f = v;
  unsigned r = c.u + 0x7fffu + ((c.u >> 16) & 1u);
  return (u16)(r >> 16);
}
__device__ inline float b2f(u16 h) {
  union { unsigned u; float f; } c; c.u = ((unsigned)h) << 16;
  return c.f;
}

// ------- conv1: x (B,L,9) -> padded f1H/f1L (B, 2050, 128) bf16 split, relu -------
__global__ __launch_bounds__(256) void k1_conv1(const float* __restrict__ x,
    const float* __restrict__ w, const float* __restrict__ bias,
    u16* __restrict__ f1H, u16* __restrict__ f1L) {
  int idx = blockIdx.x * 256 + threadIdx.x;   // b*LP*128 + tt*128 + i
  int i = idx & 127;
  int rest = idx >> 7;
  int tt = rest % LP;
  int b = rest / LP;
  if (tt == 0 || tt == LP - 1) { f1H[idx] = 0; f1L[idx] = 0; return; }
  int t = tt - 1;
  float acc = bias[i];
#pragma unroll
  for (int k = 0; k < 3; ++k) {
    int ts = t + k - 1;
    if (ts < 0 || ts >= LL) continue;
    const float* xr = x + (b * LL + ts) * 9;
    const float* wr = w + i * 27 + k;
#pragma unroll
    for (int c = 0; c < 9; ++c) acc += xr[c] * wr[c * 3];
  }
  float v = fmaxf(acc, 0.f);
  u16 h = f2b(v);
  f1H[idx] = h;
  f1L[idx] = f2b(v - b2f(h));
}

// ------- conv2 weight reorder: w (256,128,3) -> W'[o][tap*128+i] H/L -------
__global__ __launch_bounds__(256) void k_wconv2(const float* __restrict__ w,
    u16* __restrict__ H, u16* __restrict__ L) {
  int idx = blockIdx.x * 256 + threadIdx.x;   // o*384 + tap*128 + i
  if (idx >= 256 * 384) return;
  int o = idx / 384;
  int r = idx - o * 384;
  int tap = r >> 7;
  int i = r & 127;
  float v = w[o * 384 + i * 3 + tap];
  u16 h = f2b(v);
  H[idx] = h;
  L[idx] = f2b(v - b2f(h));
}

// ---------------- weight split fp32 -> bf16 H/L ----------------
__global__ __launch_bounds__(256) void k_wsplit(const float* __restrict__ w,
    u16* __restrict__ H, u16* __restrict__ L, int n) {
  int i = blockIdx.x * 256 + threadIdx.x;
  if (i >= n) return;
  float v = w[i];
  u16 h = f2b(v);
  H[i] = h;
  L[i] = f2b(v - b2f(h));
}

// ======= unified LDS-staged MFMA GEMM, bf16x2 split via 3 K-segments =======
// C[M,N] = (AH+AL)[M,K] @ (BH+BL)[N,K]^T  (AL*BL dropped)
// block tile 128 x TN, 4 waves 2x2 (wave 64 x TN/2), BK=64, double-buffered
// LDS with XOR swizzle (granule ^= row&7) -> conflict-free b128 ds ops.
template <int TN>
__global__ __launch_bounds__(256) void k_gemm3(
    const u16* __restrict__ AH, const u16* __restrict__ AL,
    const u16* __restrict__ BH, const u16* __restrict__ BL,
    float* __restrict__ C, int N, int K) {
  constexpr int WN = TN / 2;
  constexpr int NBF = WN / 16;
  constexpr int RB = TN / 32;
  __shared__ u16 As[2][128 * 64];
  __shared__ u16 Bs[2][TN * 64];
  const int tid = threadIdx.x;
  const int wid = tid >> 6, lane = tid & 63;
  const int wr = wid >> 1, wc = wid & 1;
  const int m0 = blockIdx.y * 128, n0 = blockIdx.x * TN;
  const int KS = K >> 6;
  const int NT = 3 * KS;
  const int arow = tid >> 3;      // 0..31, +32*rr per staging round
  const int ag = tid & 7;         // source granule (8 bf16)
  const int lrow = lane & 15;
  const int lg = lane >> 4;

  f32x4 acc[4][NBF] = {};
  uint4 ra[4], rb[RB];

  auto g3_load = [&](int t) {
    int seg = t / KS;
    int k0 = (t - seg * KS) << 6;
    const u16* Aseg = (seg < 2) ? AH : AL;
    const u16* Bseg = (seg == 1) ? BL : BH;
#pragma unroll
    for (int rr = 0; rr < 4; ++rr)
      ra[rr] = *(const uint4*)(Aseg + (size_t)(m0 + rr * 32 + arow) * K + k0 + ag * 8);
#pragma unroll
    for (int rr = 0; rr < RB; ++rr)
      rb[rr] = *(const uint4*)(Bseg + (size_t)(n0 + rr * 32 + arow) * K + k0 + ag * 8);
  };
  auto g3_write = [&](int buf) {
#pragma unroll
    for (int rr = 0; rr < 4; ++rr) {
      int row = rr * 32 + arow;
      *(uint4*)&As[buf][row * 64 + ((ag ^ (row & 7)) * 8)] = ra[rr];
    }
#pragma unroll
    for (int rr = 0; rr < RB; ++rr) {
      int row = rr * 32 + arow;
      *(uint4*)&Bs[buf][row * 64 + ((ag ^ (row & 7)) * 8)] = rb[rr];
    }
  };

  g3_load(0);
  g3_write(0);
  __syncthreads();
  for (int t = 0; t < NT; ++t) {
    int cur = t & 1;
    if (t + 1 < NT) g3_load(t + 1);
#pragma unroll
    for (int c = 0; c < 2; ++c) {
      bf16x8 a[4], b[NBF];
#pragma unroll
      for (int i = 0; i < 4; ++i) {
        int row = wr * 64 + i * 16 + lrow;
        int gl = c * 4 + lg;
        a[i] = *(const bf16x8*)&As[cur][row * 64 + ((gl ^ (row & 7)) * 8)];
      }
#pragma unroll
      for (int j = 0; j < NBF; ++j) {
        int row = wc * WN + j * 16 + lrow;
        int gl = c * 4 + lg;
        b[j] = *(const bf16x8*)&Bs[cur][row * 64 + ((gl ^ (row & 7)) * 8)];
      }
#pragma unroll
      for (int i = 0; i < 4; ++i)
#pragma unroll
        for (int j = 0; j < NBF; ++j)
          acc[i][j] = __builtin_amdgcn_mfma_f32_16x16x32_bf16(a[i], b[j], acc[i][j], 0, 0, 0);
    }
    if (t + 1 < NT) g3_write(cur ^ 1);
    __syncthreads();
  }
  int orow = lg << 2;
#pragma unroll
  for (int i = 0; i < 4; ++i)
#pragma unroll
    for (int j = 0; j < NBF; ++j)
#pragma unroll
      for (int r = 0; r < 4; ++r)
        C[(size_t)(m0 + wr * 64 + i * 16 + orow + r) * N + n0 + wc * WN + j * 16 + lrow] = acc[i][j][r];
}

// ======= conv2 as implicit-im2col MFMA GEMM (padded f1, no predication) =======
// tile 128 x 64, 4 waves 2x2 (wave 64x32). 3 segs x 3 taps x 2 half-K = 18 steps.
__global__ __launch_bounds__(256) void k2g_conv2(
    const u16* __restrict__ f1pH, const u16* __restrict__ f1pL,
    const u16* __restrict__ WH, const u16* __restrict__ WL,
    const float* __restrict__ bias,
    u16* __restrict__ featH, u16* __restrict__ featL) {
  __shared__ u16 As[2][128 * 64];
  __shared__ u16 Bs[2][64 * 64];
  const int tid = threadIdx.x;
  const int wid = tid >> 6, lane = tid & 63;
  const int wr = wid >> 1, wc = wid & 1;
  const int m0 = blockIdx.y * 128, n0 = blockIdx.x * 64;
  const int NT = 18;
  const int arow = tid >> 3;
  const int ag = tid & 7;
  const int lrow = lane & 15;
  const int lg = lane >> 4;

  f32x4 acc[4][2] = {};
  uint4 ra[4], rb[2];

  auto c2_load = [&](int t) {
    int seg = t / 6;
    int ks = t - seg * 6;
    int tap = ks >> 1;
    int kh = ks & 1;
    const u16* Aseg = (seg < 2) ? f1pH : f1pL;
    const u16* Bseg = (seg == 1) ? WL : WH;
#pragma unroll
    for (int rr = 0; rr < 4; ++rr) {
      int m = m0 + rr * 32 + arow;
      int b = m >> 11;
      int tq = m & (LL - 1);
      ra[rr] = *(const uint4*)(Aseg + (size_t)(b * LP + tq + tap) * 128 + kh * 64 + ag * 8);
    }
#pragma unroll
    for (int rr = 0; rr < 2; ++rr) {
      int o = n0 + rr * 32 + arow;
      rb[rr] = *(const uint4*)(Bseg + (size_t)o * 384 + tap * 128 + kh * 64 + ag * 8);
    }
  };
  auto c2_write = [&](int buf) {
#pragma unroll
    for (int rr = 0; rr < 4; ++rr) {
      int row = rr * 32 + arow;
      *(uint4*)&As[buf][row * 64 + ((ag ^ (row & 7)) * 8)] = ra[rr];
    }
#pragma unroll
    for (int rr = 0; rr < 2; ++rr) {
      int row = rr * 32 + arow;
      *(uint4*)&Bs[buf][row * 64 + ((ag ^ (row & 7)) * 8)] = rb[rr];
    }
  };

  c2_load(0);
  c2_write(0);
  __syncthreads();
  for (int t = 0; t < NT; ++t) {
    int cur = t & 1;
    if (t + 1 < NT) c2_load(t + 1);
#pragma unroll
    for (int c = 0; c < 2; ++c) {
      bf16x8 a[4], b[2];
#pragma unroll
      for (int i = 0; i < 4; ++i) {
        int row = wr * 64 + i * 16 + lrow;
        int gl = c * 4 + lg;
        a[i] = *(const bf16x8*)&As[cur][row * 64 + ((gl ^ (row & 7)) * 8)];
      }
#pragma unroll
      for (int j = 0; j < 2; ++j) {
        int row = wc * 32 + j * 16 + lrow;
        int gl = c * 4 + lg;
        b[j] = *(const bf16x8*)&Bs[cur][row * 64 + ((gl ^ (row & 7)) * 8)];
      }
#pragma unroll
      for (int i = 0; i < 4; ++i)
#pragma unroll
        for (int j = 0; j < 2; ++j)
          acc[i][j] = __builtin_amdgcn_mfma_f32_16x16x32_bf16(a[i], b[j], acc[i][j], 0, 0, 0);
    }
    if (t + 1 < NT) c2_write(cur ^ 1);
    __syncthreads();
  }
  int orow = lg << 2;
#pragma unroll
  for (int i = 0; i < 4; ++i)
#pragma unroll
    for (int j = 0; j < 2; ++j)
#pragma unroll
      for (int r = 0; r < 4; ++r) {
        int row = m0 + wr * 64 + i * 16 + orow + r;
        int o = n0 + wc * 32 + j * 16 + lrow;
        float v = fmaxf(acc[i][j][r] + bias[o], 0.f);
        u16 h = f2b(v);
        featH[(size_t)row * 256 + o] = h;
        featL[(size_t)row * 256 + o] = f2b(v - b2f(h));
      }
}

// ---------------- depthwise causal conv4 + silu: xz -> u (B,L,512) ----------------
__global__ __launch_bounds__(256) void k4_dwconv(const float* __restrict__ xz,
    const float* __restrict__ w, const float* __restrict__ bias,
    float* __restrict__ u) {
  int idx = blockIdx.x * 256 + threadIdx.x;
  int d = idx & 511;
  int t = (idx >> 9) & (LL - 1);
  int b = idx >> 20;
  float acc = bias[d];
#pragma unroll
  for (int k = 0; k < 4; ++k) {
    int tt = t - 3 + k;
    if (tt >= 0) acc += xz[(b * LL + tt) * 1024 + d] * w[d * 4 + k];
  }
  float sig = 1.f / (1.f + __expf(-acc));
  u[idx] = acc * sig;
}

// ---------------- x_proj (LDS-staged): u (8192,512) @ w(48,512)^T -> xdbl ----
__global__ __launch_bounds__(256) void k5_xproj(const float* __restrict__ u,
    const float* __restrict__ w, float* __restrict__ xdbl) {
  __shared__ float As[32][129];
  __shared__ float Ws[48][129];
  int r0 = blockIdx.x * 32;
  int tid = threadIdx.x;
  int r = tid >> 3;
  int jg = tid & 7;
  float acc[6] = {};
  for (int k0 = 0; k0 < 512; k0 += 128) {
    __syncthreads();
    for (int i = tid; i < 32 * 32; i += 256) {
      int rr = i >> 5;
      int cc = (i & 31) << 2;
      float4 v = *(const float4*)(u + (size_t)(r0 + rr) * 512 + k0 + cc);
      As[rr][cc] = v.x; As[rr][cc + 1] = v.y; As[rr][cc + 2] = v.z; As[rr][cc + 3] = v.w;
    }
    for (int i = tid; i < 48 * 32; i += 256) {
      int jj = i >> 5;
      int cc = (i & 31) << 2;
      float4 v = *(const float4*)(w + (size_t)jj * 512 + k0 + cc);
      Ws[jj][cc] = v.x; Ws[jj][cc + 1] = v.y; Ws[jj][cc + 2] = v.z; Ws[jj][cc + 3] = v.w;
    }
    __syncthreads();
    for (int k = 0; k < 128; ++k) {
      float a = As[r][k];
#pragma unroll
      for (int jj = 0; jj < 6; ++jj)
        acc[jj] += a * Ws[jg * 6 + jj][k];
    }
  }
  int row = r0 + r;
#pragma unroll
  for (int jj = 0; jj < 6; ++jj)
    xdbl[(size_t)row * 48 + jg * 6 + jj] = acc[jj];
}

// ---------------- dt: softplus(dt_lr @ dt_proj_w^T + b) -> (8192,512) ----------------
__global__ __launch_bounds__(256) void k6_dt(const float* __restrict__ xdbl,
    const float* __restrict__ w, const float* __restrict__ bias,
    float* __restrict__ dt) {
  int idx = blockIdx.x * 256 + threadIdx.x;
  int d = idx & 511;
  int row = idx >> 9;
  const float* lr = xdbl + row * 48;
  const float* wr = w + d * 16;
  float acc = bias[d];
#pragma unroll
  for (int r = 0; r < 16; ++r) acc += lr[r] * wr[r];
  dt[idx] = (acc > 20.f) ? acc : log1pf(expf(acc));
}

// ======== chunked selective scan: 3 passes ========
__global__ __launch_bounds__(512) void k7a_pass1(const float* __restrict__ dt,
    const float* __restrict__ u, const float* __restrict__ xdbl,
    const float* __restrict__ A_log, float* __restrict__ hloc,
    float* __restrict__ dtsum) {
  __shared__ float Bs[CH][16];
  int b = blockIdx.x >> 6;
  int c = blockIdx.x & (NC - 1);
  int d = threadIdx.x;
  {
    int t = threadIdx.x >> 4, s = threadIdx.x & 15;
    Bs[t][s] = xdbl[(b * LL + c * CH + t) * 48 + 16 + s];
  }
  __syncthreads();
  float A_r[16];
#pragma unroll
  for (int s = 0; s < 16; ++s) A_r[s] = -__expf(A_log[d * 16 + s]);
  float h[16];
#pragma unroll
  for (int s = 0; s < 16; ++s) h[s] = 0.f;
  float dsum = 0.f;
  const float* dtp = dt + (size_t)(b * LL + c * CH) * 512 + d;
  const float* up  = u  + (size_t)(b * LL + c * CH) * 512 + d;
  for (int t = 0; t < CH; ++t) {
    float dtv = dtp[t * 512];
    float uv  = up[t * 512];
    float xv = dtv * uv;
    dsum += dtv;
#pragma unroll
    for (int s = 0; s < 16; ++s)
      h[s] = h[s] * __expf(dtv * A_r[s]) + xv * Bs[t][s];
  }
  int base = b * NC + c;
#pragma unroll
  for (int s = 0; s < 16; ++s) hloc[(base * 16 + s) * 512 + d] = h[s];
  dtsum[base * 512 + d] = dsum;
}

__global__ __launch_bounds__(512) void k7b_combine(const float* __restrict__ hloc,
    const float* __restrict__ dtsum, const float* __restrict__ A_log,
    float* __restrict__ h_in) {
  int g = blockIdx.x * 512 + threadIdx.x;
  int d = g & 511;
  int s = (g >> 9) & 15;
  int b = g >> 13;
  float A_r = -__expf(A_log[d * 16 + s]);
  float H = 0.f;
  for (int c = 0; c < NC; ++c) {
    int base = b * NC + c;
    h_in[(base * 16 + s) * 512 + d] = H;
    float P = __expf(A_r * dtsum[base * 512 + d]);
    H = P * H + hloc[(base * 16 + s) * 512 + d];
  }
}

__global__ __launch_bounds__(512) void k7c_pass3(const float* __restrict__ dt,
    const float* __restrict__ u, const float* __restrict__ xdbl,
    const float* __restrict__ xz, const float* __restrict__ A_log,
    const float* __restrict__ D_param, const float* __restrict__ h_in,
    u16* __restrict__ y2H, u16* __restrict__ y2L) {
  __shared__ float BC[CH][32];
  int b = blockIdx.x >> 6;
  int c = blockIdx.x & (NC - 1);
  int d = threadIdx.x;
  for (int i = threadIdx.x; i < CH * 32; i += 512) {
    int t = i >> 5, j = i & 31;
    BC[t][j] = xdbl[(b * LL + c * CH + t) * 48 + 16 + j];
  }
  __syncthreads();
  float A_r[16];
#pragma unroll
  for (int s = 0; s < 16; ++s) A_r[s] = -__expf(A_log[d * 16 + s]);
  float Dv = D_param[d];
  int base = b * NC + c;
  float h[16];
#pragma unroll
  for (int s = 0; s < 16; ++s) h[s] = h_in[(base * 16 + s) * 512 + d];
  for (int t = 0; t < CH; ++t) {
    int row = b * LL + c * CH + t;
    float dtv = dt[(size_t)row * 512 + d];
    float uv  = u[(size_t)row * 512 + d];
    float xv = dtv * uv;
    float y = 0.f;
#pragma unroll
    for (int s = 0; s < 16; ++s) {
      h[s] = h[s] * __expf(dtv * A_r[s]) + xv * BC[t][s];
      y += h[s] * BC[t][16 + s];
    }
    float zv = xz[(size_t)row * 1024 + 512 + d];
    float sig = 1.f / (1.f + __expf(-zv));
    float v = (y + Dv * uv) * (zv * sig);
    u16 hh = f2b(v);
    y2H[(size_t)row * 512 + d] = hh;
    y2L[(size_t)row * 512 + d] = f2b(v - b2f(hh));
  }
}

// ---------------- partial max over t-chunks: mo (B,L,256) -> part (B*32,256) ----------------
__global__ __launch_bounds__(256) void k9_pmax(const float* __restrict__ mo,
    float* __restrict__ part) {
  int blk = blockIdx.x;
  int b = blk >> 5;
  int ch = blk & 31;
  int o = threadIdx.x;
  float m = -FLT_MAX;
  for (int tt = 0; tt < 64; ++tt)
    m = fmaxf(m, mo[(b * LL + ch * 64 + tt) * 256 + o]);
  part[blk * 256 + o] = m;
}

// ---------------- final: max-reduce + fc1 relu + fc2 -> out (4,4) ----------------
__global__ __launch_bounds__(256) void k10_head(const float* __restrict__ part,
    const float* __restrict__ fc1_w, const float* __restrict__ fc1_b,
    const float* __restrict__ fc2_w, const float* __restrict__ fc2_b,
    float* __restrict__ out) {
  __shared__ float pooled[4][256];
  __shared__ float hbuf[4][128];
  int tid = threadIdx.x;
  for (int idx = tid; idx < 1024; idx += 256) {
    int b = idx >> 8, o = idx & 255;
    float m = -FLT_MAX;
    for (int c = 0; c < 32; ++c) m = fmaxf(m, part[(b * 32 + c) * 256 + o]);
    pooled[b][o] = m;
  }
  __syncthreads();
  for (int idx = tid; idx < 512; idx += 256) {
    int b = idx >> 7, i = idx & 127;
    float acc = fc1_b[i];
    for (int o = 0; o < 256; ++o) acc += pooled[b][o] * fc1_w[i * 256 + o];
    hbuf[b][i] = fmaxf(acc, 0.f);
  }
  __syncthreads();
  if (tid < 16) {
    int b = tid >> 2, c = tid & 3;
    float acc = fc2_b[c];
    for (int i = 0; i < 128; ++i) acc += hbuf[b][i] * fc2_w[c * 128 + i];
    out[b * 4 + c] = acc;
  }
}

extern "C" void kernel_launch(void* const* d_in, const int* in_sizes, int n_in,
                              void* d_out, int out_size, void* d_ws, size_t ws_size,
                              hipStream_t stream) {
  (void)in_sizes; (void)n_in; (void)out_size; (void)ws_size;
  const float* x        = (const float*)d_in[0];
  const float* conv1_w  = (const float*)d_in[1];
  const float* conv1_b  = (const float*)d_in[2];
  const float* conv2_w  = (const float*)d_in[3];
  const float* conv2_b  = (const float*)d_in[4];
  const float* in_proj_w= (const float*)d_in[5];
  const float* dw_w     = (const float*)d_in[6];
  const float* dw_b     = (const float*)d_in[7];
  const float* x_proj_w = (const float*)d_in[8];
  const float* dt_proj_w= (const float*)d_in[9];
  const float* dt_proj_b= (const float*)d_in[10];
  const float* A_log    = (const float*)d_in[11];
  const float* D_param  = (const float*)d_in[12];
  const float* out_proj_w=(const float*)d_in[13];
  const float* fc1_w    = (const float*)d_in[14];
  const float* fc1_b    = (const float*)d_in[15];
  const float* fc2_w    = (const float*)d_in[16];
  const float* fc2_b    = (const float*)d_in[17];
  float* out = (float*)d_out;

  float* ws = (float*)d_ws;
  float* f1   = ws;                    // 1048576 floats: dtsum + out_proj wt split
  float* feat = f1 + 1048576;          // 2097152: featH/featL bf16, later h_in
  float* xz   = feat + 2097152;        // 8388608
  float* u    = xz + 8388608;          // 4194304 (in_proj wH/wL before k4 writes)
  float* xdbl = u + 4194304;           // 393216
  float* dt   = xdbl + 393216;         // 4194304
  float* y2   = dt + 4194304;          // 4194304: y2H/y2L bf16
  float* mo   = y2 + 4194304;          // 2097152 (conv2 W' early, hloc mid)
  float* part = mo + 2097152;          // 32768
  float* f1p  = part + 32768;          // padded f1 bf16 H/L: 1,049,600 floats

  float* hloc  = mo;                   // k7a->k7b; dead before out_proj
  float* h_in  = feat;                 // feat dead after in_proj
  float* dtsum = f1;                   // f1[0:131072)

  u16* f1pH  = (u16*)f1p;              // 4*2050*128 = 1,049,600 elems
  u16* f1pL  = f1pH + BB * LP * 128;
  u16* featH = (u16*)feat;
  u16* featL = (u16*)(feat + 1048576);
  u16* wH    = (u16*)u;                // in_proj: 262144 elems each
  u16* wL    = wH + 262144;
  u16* wc2H  = (u16*)mo;               // conv2 W': 98304 elems each
  u16* wc2L  = wc2H + 98304;
  u16* owH   = (u16*)(f1 + 262144);    // out_proj: 131072 elems each
  u16* owL   = owH + 131072;
  u16* y2H   = (u16*)y2;
  u16* y2L   = (u16*)(y2 + 2097152);

  k1_conv1<<<dim3(BB * LP * 128 / 256), dim3(256), 0, stream>>>(x, conv1_w, conv1_b, f1pH, f1pL);
  k_wconv2<<<dim3((256 * 384 + 255) / 256), dim3(256), 0, stream>>>(conv2_w, wc2H, wc2L);
  k2g_conv2<<<dim3(4, 64), dim3(256), 0, stream>>>(f1pH, f1pL, wc2H, wc2L, conv2_b, featH, featL);
  k_wsplit<<<dim3(262144 / 256), dim3(256), 0, stream>>>(in_proj_w, wH, wL, 262144);
  k_wsplit<<<dim3(131072 / 256), dim3(256), 0, stream>>>(out_proj_w, owH, owL, 131072);
  // in_proj: (8192,256)x(1024,256)^T -> xz
  k_gemm3<128><<<dim3(1024 / 128, 8192 / 128), dim3(256), 0, stream>>>(featH, featL, wH, wL, xz, 1024, 256);
  k4_dwconv<<<dim3(BB * LL * 512 / 256), dim3(256), 0, stream>>>(xz, dw_w, dw_b, u);
  k5_xproj<<<dim3(256), dim3(256), 0, stream>>>(u, x_proj_w, xdbl);
  k6_dt<<<dim3(BB * LL * 512 / 256), dim3(256), 0, stream>>>(xdbl, dt_proj_w, dt_proj_b, dt);
  k7a_pass1<<<dim3(BB * NC), dim3(512), 0, stream>>>(dt, u, xdbl, A_log, hloc, dtsum);
  k7b_combine<<<dim3(BB * 16), dim3(512), 0, stream>>>(hloc, dtsum, A_log, h_in);
  k7c_pass3<<<dim3(BB * NC), dim3(512), 0, stream>>>(dt, u, xdbl, xz, A_log, D_param, h_in, y2H, y2L);
  // out_proj: (8192,512)x(256,512)^T -> mo
  k_gemm3<64><<<dim3(256 / 64, 8192 / 128), dim3(256), 0, stream>>>(y2H, y2L, owH, owL, mo, 256, 512);
  k9_pmax<<<dim3(128), dim3(256), 0, stream>>>(mo, part);
  k10_head<<<dim3(1), dim3(256), 0, stream>>>(part, fc1_w, fc1_b, fc2_w, fc2_b, out);
}

// Round 7
// 278.830 us; speedup vs baseline: 1.2719x; 1.2719x over previous
//
#include <hip/hip_runtime.h>
#include <cfloat>

#define BB 4
#define LL 2048
#define DMODEL 256
#define DINNER 512
#define DSTATE 16
#define DTRANK 16
#define HID 128
#define NCLS 4
#define CH 32
#define NC 64

typedef unsigned short u16;
typedef __attribute__((ext_vector_type(8))) short bf16x8;
typedef __attribute__((ext_vector_type(4))) float f32x4;

__device__ inline u16 f2b(float v) {
  union { float f; unsigned u; } c; c.f = v;
  unsigned r = c.u + 0x7fffu + ((c.u >> 16) & 1u);
  return (u16)(r >> 16);
}
__device__ inline float b2f(u16 h) {
  union { unsigned u; float f; } c; c.u = ((unsigned)h) << 16;
  return c.f;
}

// async global->LDS, 16B per lane (dest = wave-uniform base + lane*16)
#define GLOAD16(gsrc, ldst) \
  __builtin_amdgcn_global_load_lds( \
      (const __attribute__((address_space(1))) unsigned int*)(gsrc), \
      (__attribute__((address_space(3))) unsigned int*)(ldst), 16, 0, 0)

// ------- conv1: x (B,L,9) -> f1H/f1L (B,L,128) bf16 split, relu -------
__global__ __launch_bounds__(256) void k1_conv1(const float* __restrict__ x,
    const float* __restrict__ w, const float* __restrict__ bias,
    u16* __restrict__ f1H, u16* __restrict__ f1L) {
  int idx = blockIdx.x * 256 + threadIdx.x;
  int i = idx & 127;
  int t = (idx >> 7) & (LL - 1);
  int b = idx >> 18;
  float acc = bias[i];
#pragma unroll
  for (int k = 0; k < 3; ++k) {
    int ts = t + k - 1;
    if (ts < 0 || ts >= LL) continue;
    const float* xr = x + (b * LL + ts) * 9;
    const float* wr = w + i * 27 + k;
#pragma unroll
    for (int c = 0; c < 9; ++c) acc += xr[c] * wr[c * 3];
  }
  float v = fmaxf(acc, 0.f);
  u16 h = f2b(v);
  f1H[idx] = h;
  f1L[idx] = f2b(v - b2f(h));
}

// ------- im2col for conv2: f1 -> A' (8192, 1152) = [Htaps | Ltaps | Htaps] -------
__global__ __launch_bounds__(256) void k_im2col(const u16* __restrict__ f1H,
    const u16* __restrict__ f1L, u16* __restrict__ dst) {
  int row = blockIdx.x;                 // 8192
  int b = row >> 11, t = row & (LL - 1);
  u16* rp = dst + (size_t)row * 1152;
  for (int idx = threadIdx.x; idx < 384; idx += 256) {
    int tap = idx >> 7, i = idx & 127;
    int ts = t + tap - 1;
    u16 h = 0, l = 0;
    if (ts >= 0 && ts < LL) {
      h = f1H[((size_t)b * LL + ts) * 128 + i];
      l = f1L[((size_t)b * LL + ts) * 128 + i];
    }
    rp[idx] = h;
    rp[384 + idx] = l;
    rp[768 + idx] = h;
  }
}

// ------- conv2 weights: (256,128,3) -> (256, 1152) = [WHtaps | WHtaps | WLtaps] -------
__global__ __launch_bounds__(256) void k_wconv2_3(const float* __restrict__ w,
    u16* __restrict__ dst) {
  int idx = blockIdx.x * 256 + threadIdx.x;   // o*384 + tap*128 + i
  if (idx >= 256 * 384) return;
  int o = idx / 384, r = idx - o * 384;
  int tap = r >> 7, i = r & 127;
  float v = w[o * 384 + i * 3 + tap];
  u16 h = f2b(v), l = f2b(v - b2f(h));
  u16* rp = dst + (size_t)o * 1152;
  rp[r] = h;
  rp[384 + r] = h;
  rp[768 + r] = l;
}

// ------- generic weights: w (N,K) fp32 -> (N, 3K) = [WH | WH | WL] -------
__global__ __launch_bounds__(256) void k_wsplit3(const float* __restrict__ w,
    u16* __restrict__ dst, int NK, int K) {
  int idx = blockIdx.x * 256 + threadIdx.x;
  if (idx >= NK) return;
  int n = idx / K, k = idx - n * K;
  float v = w[idx];
  u16 h = f2b(v), l = f2b(v - b2f(h));
  u16* rp = dst + (size_t)n * 3 * K;
  rp[k] = h;
  rp[K + k] = h;
  rp[2 * K + k] = l;
}

// ======= m97-style MFMA GEMM: C[M,N] = A'[M,K'] @ B'[N,K']^T =======
// 128 x TN tile, 4 waves (2x2), BK=64, global_load_lds(16B) staging with
// source-side XOR pre-swizzle + matching XOR on LDS reads, double-buffered,
// one barrier per K-step, bijective XCD blockIdx swizzle (nwg % 8 == 0).
// EPI 0: plain fp32 C.  EPI 1: conv2 epilogue (bias+relu, write feat'=[H|L|H]).
template <int TN, int EPI, int NBX>
__global__ __launch_bounds__(256) void k_mm(
    const u16* __restrict__ A, const u16* __restrict__ B,
    float* __restrict__ C, const float* __restrict__ bias,
    u16* __restrict__ osp, int N, int K) {
  constexpr int WN = TN / 2;
  constexpr int NB = WN / 16;
  __shared__ u16 As[2][128 * 64];
  __shared__ u16 Bs[2][TN * 64];
  const int tid = threadIdx.x;
  const int lane = tid & 63;
  const int wid = tid >> 6;
  const int wr = wid >> 1, wc = wid & 1;
  int bid = blockIdx.y * NBX + blockIdx.x;
  int nwg = gridDim.y * NBX;
  int swz = (bid & 7) * (nwg >> 3) + (bid >> 3);
  int bn = swz & (NBX - 1), bm = swz / NBX;
  const int m0 = bm * 128, n0 = bn * TN;
  const int lrow = lane & 15, lg = lane >> 4;
  const int srow = tid >> 3, sg = tid & 7;
  const int NT = K >> 6;

  f32x4 acc[4][NB] = {};

  auto stage = [&](int buf, int k0) {
#pragma unroll
    for (int r = 0; r < 4; ++r) {
      int row = r * 32 + srow;
      const u16* src = A + (size_t)(m0 + row) * K + k0 + ((sg ^ (row & 7)) << 3);
      GLOAD16(src, &As[buf][row * 64 + (sg << 3)]);
    }
#pragma unroll
    for (int r = 0; r < TN / 32; ++r) {
      int row = r * 32 + srow;
      const u16* src = B + (size_t)(n0 + row) * K + k0 + ((sg ^ (row & 7)) << 3);
      GLOAD16(src, &Bs[buf][row * 64 + (sg << 3)]);
    }
  };

  stage(0, 0);
  __syncthreads();
  for (int t = 0; t < NT; ++t) {
    int cur = t & 1;
    if (t + 1 < NT) stage(cur ^ 1, (t + 1) << 6);
#pragma unroll
    for (int kc = 0; kc < 2; ++kc) {
      bf16x8 af[4], bfr[NB];
#pragma unroll
      for (int i = 0; i < 4; ++i) {
        int row = wr * 64 + i * 16 + lrow;
        int g = (kc * 4 + lg) ^ (row & 7);
        af[i] = *(const bf16x8*)&As[cur][row * 64 + (g << 3)];
      }
#pragma unroll
      for (int j = 0; j < NB; ++j) {
        int row = wc * WN + j * 16 + lrow;
        int g = (kc * 4 + lg) ^ (row & 7);
        bfr[j] = *(const bf16x8*)&Bs[cur][row * 64 + (g << 3)];
      }
#pragma unroll
      for (int i = 0; i < 4; ++i)
#pragma unroll
        for (int j = 0; j < NB; ++j)
          acc[i][j] = __builtin_amdgcn_mfma_f32_16x16x32_bf16(af[i], bfr[j], acc[i][j], 0, 0, 0);
    }
    __syncthreads();
  }
#pragma unroll
  for (int i = 0; i < 4; ++i)
#pragma unroll
    for (int j = 0; j < NB; ++j)
#pragma unroll
      for (int r = 0; r < 4; ++r) {
        int row = m0 + wr * 64 + i * 16 + lg * 4 + r;
        int col = n0 + wc * WN + j * 16 + lrow;
        if constexpr (EPI == 0) {
          C[(size_t)row * N + col] = acc[i][j][r];
        } else {
          float v = fmaxf(acc[i][j][r] + bias[col], 0.f);
          u16 h = f2b(v), l = f2b(v - b2f(h));
          u16* rp = osp + (size_t)row * 768;
          rp[col] = h;
          rp[256 + col] = l;
          rp[512 + col] = h;
        }
      }
}

// ---------------- depthwise causal conv4 + silu: xz -> u (B,L,512) ----------------
__global__ __launch_bounds__(256) void k4_dwconv(const float* __restrict__ xz,
    const float* __restrict__ w, const float* __restrict__ bias,
    float* __restrict__ u) {
  int idx = blockIdx.x * 256 + threadIdx.x;
  int d = idx & 511;
  int t = (idx >> 9) & (LL - 1);
  int b = idx >> 20;
  float acc = bias[d];
#pragma unroll
  for (int k = 0; k < 4; ++k) {
    int tt = t - 3 + k;
    if (tt >= 0) acc += xz[(b * LL + tt) * 1024 + d] * w[d * 4 + k];
  }
  float sig = 1.f / (1.f + __expf(-acc));
  u[idx] = acc * sig;
}

// ---------------- x_proj (LDS-staged): u (8192,512) @ w(48,512)^T -> xdbl ----
__global__ __launch_bounds__(256) void k5_xproj(const float* __restrict__ u,
    const float* __restrict__ w, float* __restrict__ xdbl) {
  __shared__ float As[32][129];
  __shared__ float Ws[48][129];
  int r0 = blockIdx.x * 32;
  int tid = threadIdx.x;
  int r = tid >> 3;
  int jg = tid & 7;
  float acc[6] = {};
  for (int k0 = 0; k0 < 512; k0 += 128) {
    __syncthreads();
    for (int i = tid; i < 32 * 32; i += 256) {
      int rr = i >> 5;
      int cc = (i & 31) << 2;
      float4 v = *(const float4*)(u + (size_t)(r0 + rr) * 512 + k0 + cc);
      As[rr][cc] = v.x; As[rr][cc + 1] = v.y; As[rr][cc + 2] = v.z; As[rr][cc + 3] = v.w;
    }
    for (int i = tid; i < 48 * 32; i += 256) {
      int jj = i >> 5;
      int cc = (i & 31) << 2;
      float4 v = *(const float4*)(w + (size_t)jj * 512 + k0 + cc);
      Ws[jj][cc] = v.x; Ws[jj][cc + 1] = v.y; Ws[jj][cc + 2] = v.z; Ws[jj][cc + 3] = v.w;
    }
    __syncthreads();
    for (int k = 0; k < 128; ++k) {
      float a = As[r][k];
#pragma unroll
      for (int jj = 0; jj < 6; ++jj)
        acc[jj] += a * Ws[jg * 6 + jj][k];
    }
  }
  int row = r0 + r;
#pragma unroll
  for (int jj = 0; jj < 6; ++jj)
    xdbl[(size_t)row * 48 + jg * 6 + jj] = acc[jj];
}

// ---------------- dt: softplus(dt_lr @ dt_proj_w^T + b) -> (8192,512) ----------------
__global__ __launch_bounds__(256) void k6_dt(const float* __restrict__ xdbl,
    const float* __restrict__ w, const float* __restrict__ bias,
    float* __restrict__ dt) {
  int idx = blockIdx.x * 256 + threadIdx.x;
  int d = idx & 511;
  int row = idx >> 9;
  const float* lr = xdbl + row * 48;
  const float* wr = w + d * 16;
  float acc = bias[d];
#pragma unroll
  for (int r = 0; r < 16; ++r) acc += lr[r] * wr[r];
  dt[idx] = (acc > 20.f) ? acc : log1pf(expf(acc));
}

// ======== chunked selective scan: 3 passes ========
__global__ __launch_bounds__(512) void k7a_pass1(const float* __restrict__ dt,
    const float* __restrict__ u, const float* __restrict__ xdbl,
    const float* __restrict__ A_log, float* __restrict__ hloc,
    float* __restrict__ dtsum) {
  __shared__ float Bs[CH][16];
  int b = blockIdx.x >> 6;
  int c = blockIdx.x & (NC - 1);
  int d = threadIdx.x;
  {
    int t = threadIdx.x >> 4, s = threadIdx.x & 15;
    Bs[t][s] = xdbl[(b * LL + c * CH + t) * 48 + 16 + s];
  }
  __syncthreads();
  float A_r[16];
#pragma unroll
  for (int s = 0; s < 16; ++s) A_r[s] = -__expf(A_log[d * 16 + s]);
  float h[16];
#pragma unroll
  for (int s = 0; s < 16; ++s) h[s] = 0.f;
  float dsum = 0.f;
  const float* dtp = dt + (size_t)(b * LL + c * CH) * 512 + d;
  const float* up  = u  + (size_t)(b * LL + c * CH) * 512 + d;
  for (int t = 0; t < CH; ++t) {
    float dtv = dtp[t * 512];
    float uv  = up[t * 512];
    float xv = dtv * uv;
    dsum += dtv;
#pragma unroll
    for (int s = 0; s < 16; ++s)
      h[s] = h[s] * __expf(dtv * A_r[s]) + xv * Bs[t][s];
  }
  int base = b * NC + c;
#pragma unroll
  for (int s = 0; s < 16; ++s) hloc[(base * 16 + s) * 512 + d] = h[s];
  dtsum[base * 512 + d] = dsum;
}

__global__ __launch_bounds__(512) void k7b_combine(const float* __restrict__ hloc,
    const float* __restrict__ dtsum, const float* __restrict__ A_log,
    float* __restrict__ h_in) {
  int g = blockIdx.x * 512 + threadIdx.x;
  int d = g & 511;
  int s = (g >> 9) & 15;
  int b = g >> 13;
  float A_r = -__expf(A_log[d * 16 + s]);
  float H = 0.f;
  for (int c = 0; c < NC; ++c) {
    int base = b * NC + c;
    h_in[(base * 16 + s) * 512 + d] = H;
    float P = __expf(A_r * dtsum[base * 512 + d]);
    H = P * H + hloc[(base * 16 + s) * 512 + d];
  }
}

// pass3: replay + gate; writes y2' (8192,1536) = [H | L | H] for out_proj
__global__ __launch_bounds__(512) void k7c_pass3(const float* __restrict__ dt,
    const float* __restrict__ u, const float* __restrict__ xdbl,
    const float* __restrict__ xz, const float* __restrict__ A_log,
    const float* __restrict__ D_param, const float* __restrict__ h_in,
    u16* __restrict__ y2s) {
  __shared__ float BC[CH][32];
  int b = blockIdx.x >> 6;
  int c = blockIdx.x & (NC - 1);
  int d = threadIdx.x;
  for (int i = threadIdx.x; i < CH * 32; i += 512) {
    int t = i >> 5, j = i & 31;
    BC[t][j] = xdbl[(b * LL + c * CH + t) * 48 + 16 + j];
  }
  __syncthreads();
  float A_r[16];
#pragma unroll
  for (int s = 0; s < 16; ++s) A_r[s] = -__expf(A_log[d * 16 + s]);
  float Dv = D_param[d];
  int base = b * NC + c;
  float h[16];
#pragma unroll
  for (int s = 0; s < 16; ++s) h[s] = h_in[(base * 16 + s) * 512 + d];
  for (int t = 0; t < CH; ++t) {
    int row = b * LL + c * CH + t;
    float dtv = dt[(size_t)row * 512 + d];
    float uv  = u[(size_t)row * 512 + d];
    float xv = dtv * uv;
    float y = 0.f;
#pragma unroll
    for (int s = 0; s < 16; ++s) {
      h[s] = h[s] * __expf(dtv * A_r[s]) + xv * BC[t][s];
      y += h[s] * BC[t][16 + s];
    }
    float zv = xz[(size_t)row * 1024 + 512 + d];
    float sig = 1.f / (1.f + __expf(-zv));
    float v = (y + Dv * uv) * (zv * sig);
    u16 hh = f2b(v);
    u16 ll = f2b(v - b2f(hh));
    u16* rp = y2s + (size_t)row * 1536 + d;
    rp[0] = hh;
    rp[512] = ll;
    rp[1024] = hh;
  }
}

// ---------------- partial max over t-chunks: mo (B,L,256) -> part (B*32,256) ----------------
__global__ __launch_bounds__(256) void k9_pmax(const float* __restrict__ mo,
    float* __restrict__ part) {
  int blk = blockIdx.x;
  int b = blk >> 5;
  int ch = blk & 31;
  int o = threadIdx.x;
  float m = -FLT_MAX;
  for (int tt = 0; tt < 64; ++tt)
    m = fmaxf(m, mo[(b * LL + ch * 64 + tt) * 256 + o]);
  part[blk * 256 + o] = m;
}

// ---------------- final: max-reduce + fc1 relu + fc2 -> out (4,4) ----------------
__global__ __launch_bounds__(256) void k10_head(const float* __restrict__ part,
    const float* __restrict__ fc1_w, const float* __restrict__ fc1_b,
    const float* __restrict__ fc2_w, const float* __restrict__ fc2_b,
    float* __restrict__ out) {
  __shared__ float pooled[4][256];
  __shared__ float hbuf[4][128];
  int tid = threadIdx.x;
  for (int idx = tid; idx < 1024; idx += 256) {
    int b = idx >> 8, o = idx & 255;
    float m = -FLT_MAX;
    for (int c = 0; c < 32; ++c) m = fmaxf(m, part[(b * 32 + c) * 256 + o]);
    pooled[b][o] = m;
  }
  __syncthreads();
  for (int idx = tid; idx < 512; idx += 256) {
    int b = idx >> 7, i = idx & 127;
    float acc = fc1_b[i];
    for (int o = 0; o < 256; ++o) acc += pooled[b][o] * fc1_w[i * 256 + o];
    hbuf[b][i] = fmaxf(acc, 0.f);
  }
  __syncthreads();
  if (tid < 16) {
    int b = tid >> 2, c = tid & 3;
    float acc = fc2_b[c];
    for (int i = 0; i < 128; ++i) acc += hbuf[b][i] * fc2_w[c * 128 + i];
    out[b * 4 + c] = acc;
  }
}

extern "C" void kernel_launch(void* const* d_in, const int* in_sizes, int n_in,
                              void* d_out, int out_size, void* d_ws, size_t ws_size,
                              hipStream_t stream) {
  (void)in_sizes; (void)n_in; (void)out_size; (void)ws_size;
  const float* x        = (const float*)d_in[0];
  const float* conv1_w  = (const float*)d_in[1];
  const float* conv1_b  = (const float*)d_in[2];
  const float* conv2_w  = (const float*)d_in[3];
  const float* conv2_b  = (const float*)d_in[4];
  const float* in_proj_w= (const float*)d_in[5];
  const float* dw_w     = (const float*)d_in[6];
  const float* dw_b     = (const float*)d_in[7];
  const float* x_proj_w = (const float*)d_in[8];
  const float* dt_proj_w= (const float*)d_in[9];
  const float* dt_proj_b= (const float*)d_in[10];
  const float* A_log    = (const float*)d_in[11];
  const float* D_param  = (const float*)d_in[12];
  const float* out_proj_w=(const float*)d_in[13];
  const float* fc1_w    = (const float*)d_in[14];
  const float* fc1_b    = (const float*)d_in[15];
  const float* fc2_w    = (const float*)d_in[16];
  const float* fc2_b    = (const float*)d_in[17];
  float* out = (float*)d_out;

  // distinct regions, no aliasing (total ~158 MB)
  float* ws   = (float*)d_ws;
  float* f1   = ws;                       // 1,048,576 f (f1H + f1L u16)
  float* f1A  = f1 + 1048576;             // 4,718,592 f (8192 x 1152 u16)
  float* fe   = f1A + 4718592;            // 3,145,728 f (feat' 8192 x 768 u16)
  float* wc2  = fe + 3145728;             //   147,456 f (256 x 1152 u16)
  float* wi   = wc2 + 147456;             //   393,216 f (1024 x 768 u16)
  float* wo   = wi + 393216;              //   196,608 f (256 x 1536 u16)
  float* xz   = wo + 196608;              // 8,388,608 f
  float* u    = xz + 8388608;             // 4,194,304 f
  float* xdbl = u + 4194304;              //   393,216 f
  float* dt   = xdbl + 393216;            // 4,194,304 f
  float* y2s  = dt + 4194304;             // 6,291,456 f (8192 x 1536 u16)
  float* mo   = y2s + 6291456;            // 2,097,152 f
  float* part = mo + 2097152;             //    32,768 f
  float* hloc = part + 32768;             // 2,097,152 f
  float* h_in = hloc + 2097152;           // 2,097,152 f
  float* dts  = h_in + 2097152;           //   131,072 f

  u16* f1H  = (u16*)f1;
  u16* f1L  = f1H + 1048576;
  u16* f1Ap = (u16*)f1A;
  u16* fep  = (u16*)fe;
  u16* wc2p = (u16*)wc2;
  u16* wip  = (u16*)wi;
  u16* wop  = (u16*)wo;
  u16* y2p  = (u16*)y2s;

  k1_conv1<<<dim3(BB * LL * 128 / 256), dim3(256), 0, stream>>>(x, conv1_w, conv1_b, f1H, f1L);
  k_im2col<<<dim3(BB * LL), dim3(256), 0, stream>>>(f1H, f1L, f1Ap);
  k_wconv2_3<<<dim3(384), dim3(256), 0, stream>>>(conv2_w, wc2p);
  // conv2: (8192,1152) x (256,1152)^T -> feat' (EPI=1 epilogue)
  k_mm<64, 1, 4><<<dim3(4, 64), dim3(256), 0, stream>>>(f1Ap, wc2p, nullptr, conv2_b, fep, 256, 1152);
  k_wsplit3<<<dim3(1024), dim3(256), 0, stream>>>(in_proj_w, wip, 262144, 256);
  // in_proj: (8192,768) x (1024,768)^T -> xz
  k_mm<128, 0, 8><<<dim3(8, 64), dim3(256), 0, stream>>>(fep, wip, xz, nullptr, nullptr, 1024, 768);
  k4_dwconv<<<dim3(BB * LL * 512 / 256), dim3(256), 0, stream>>>(xz, dw_w, dw_b, u);
  k5_xproj<<<dim3(256), dim3(256), 0, stream>>>(u, x_proj_w, xdbl);
  k6_dt<<<dim3(BB * LL * 512 / 256), dim3(256), 0, stream>>>(xdbl, dt_proj_w, dt_proj_b, dt);
  k7a_pass1<<<dim3(BB * NC), dim3(512), 0, stream>>>(dt, u, xdbl, A_log, hloc, dts);
  k7b_combine<<<dim3(BB * 16), dim3(512), 0, stream>>>(hloc, dts, A_log, h_in);
  k7c_pass3<<<dim3(BB * NC), dim3(512), 0, stream>>>(dt, u, xdbl, xz, A_log, D_param, h_in, y2p);
  k_wsplit3<<<dim3(512), dim3(256), 0, stream>>>(out_proj_w, wop, 131072, 512);
  // out_proj: (8192,1536) x (256,1536)^T -> mo
  k_mm<64, 0, 4><<<dim3(4, 64), dim3(256), 0, stream>>>(y2p, wop, mo, nullptr, nullptr, 256, 1536);
  k9_pmax<<<dim3(128), dim3(256), 0, stream>>>(mo, part);
  k10_head<<<dim3(1), dim3(256), 0, stream>>>(part, fc1_w, fc1_b, fc2_w, fc2_b, out);
}